// Round 1
// 123.972 us; speedup vs baseline: 1.0680x; 1.0680x over previous
//
#include <hip/hip_runtime.h>
#include <cmath>

#define N_ROWS 2048
#define DIM 4096
#define ROW_STRIDE 8192   // features[:,0,:] -> row i at offset i*2*4096
#define NCLS 8

__device__ __forceinline__ float wred_sum(float v){
  #pragma unroll
  for(int o=32;o>0;o>>=1) v += __shfl_xor(v,o,64);
  return v;
}
__device__ __forceinline__ float wred_max(float v){
  #pragma unroll
  for(int o=32;o>0;o>>=1) v = fmaxf(v,__shfl_xor(v,o,64));
  return v;
}

// One block per row: compute lse[row] and diag[row] = sum p*logp in a single
// fused pass: S = sum e^{x-m}, T1 = sum (x-m)e^{x-m};
//   lse  = m + log S
//   diag = T1/S - log S
// Blocks 0..63 also zero the 65536-float P/L accumulator region.
__global__ __launch_bounds__(256) void k1_rowstats(
    const float* __restrict__ feat, float* __restrict__ lse,
    float* __restrict__ diag, float* __restrict__ zero_region){
  const int t = threadIdx.x;
  const int row = blockIdx.x;
  const int wave = t>>6, lane = t&63;
  if(row < 64){
    float4* z = (float4*)zero_region;
    z[row*256 + t] = make_float4(0.f,0.f,0.f,0.f);
  }
  const float4* x4 = (const float4*)(feat + (size_t)row * ROW_STRIDE);
  float4 v[4];
  #pragma unroll
  for(int k=0;k<4;k++) v[k] = x4[t + k*256];

  __shared__ float red[8];   // [0..3]=per-wave S (or max), [4..7]=per-wave T1
  // ---- max ----
  float m = -INFINITY;
  #pragma unroll
  for(int k=0;k<4;k++)
    m = fmaxf(m, fmaxf(fmaxf(v[k].x,v[k].y), fmaxf(v[k].z,v[k].w)));
  m = wred_max(m);
  if(lane==0) red[wave] = m;
  __syncthreads();
  m = fmaxf(fmaxf(red[0],red[1]), fmaxf(red[2],red[3]));
  __syncthreads();
  // ---- fused S and T1 ----
  float s = 0.f, t1 = 0.f;
  #pragma unroll
  for(int k=0;k<4;k++){
    float a=v[k].x-m, b=v[k].y-m, c=v[k].z-m, d2=v[k].w-m;
    float ea=__expf(a), eb=__expf(b), ec=__expf(c), ed=__expf(d2);
    s  += ea + eb + ec + ed;
    t1 += a*ea + b*eb + c*ec + d2*ed;
  }
  s  = wred_sum(s);
  t1 = wred_sum(t1);
  if(lane==0){ red[wave] = s; red[4+wave] = t1; }
  __syncthreads();
  if(t==0){
    float S  = red[0]+red[1]+red[2]+red[3];
    float T1 = red[4]+red[5]+red[6]+red[7];
    float lg = __logf(S);
    lse[row]  = m + lg;
    diag[row] = T1/S - lg;
  }
}

// grid (DIM/256, 64): thread owns column d, iterates a 32-row chunk,
// accumulates per-class P (sum of p) and L (sum of logp) in registers,
// then 16 global atomics. 1024 blocks -> 4 blocks/CU (vs 2 before),
// unroll 8 for deeper memory-level parallelism.
__global__ __launch_bounds__(256,4) void k2_accum(
    const float* __restrict__ feat, const float* __restrict__ lse,
    const int* __restrict__ labels,
    float* __restrict__ Pbuf, float* __restrict__ Lbuf){
  const int d = blockIdx.x * 256 + threadIdx.x;
  const int r0 = blockIdx.y * 32;
  float P0=0,P1=0,P2=0,P3=0,P4=0,P5=0,P6=0,P7=0;
  float L0=0,L1=0,L2=0,L3=0,L4=0,L5=0,L6=0,L7=0;
  const float* col = feat + (size_t)r0 * ROW_STRIDE + d;
  #pragma unroll 8
  for(int i=0;i<32;i++){
    const int r = r0 + i;
    float x = col[(size_t)i * ROW_STRIDE];
    float v = x - lse[r];
    float e = __expf(v);
    int lab = __builtin_amdgcn_readfirstlane(labels[r]); // wave-uniform -> scalar branch
    switch(lab){
      case 0: P0+=e; L0+=v; break;
      case 1: P1+=e; L1+=v; break;
      case 2: P2+=e; L2+=v; break;
      case 3: P3+=e; L3+=v; break;
      case 4: P4+=e; L4+=v; break;
      case 5: P5+=e; L5+=v; break;
      case 6: P6+=e; L6+=v; break;
      default: P7+=e; L7+=v; break;
    }
  }
  atomicAdd(&Pbuf[0*DIM+d],P0); atomicAdd(&Lbuf[0*DIM+d],L0);
  atomicAdd(&Pbuf[1*DIM+d],P1); atomicAdd(&Lbuf[1*DIM+d],L1);
  atomicAdd(&Pbuf[2*DIM+d],P2); atomicAdd(&Lbuf[2*DIM+d],L2);
  atomicAdd(&Pbuf[3*DIM+d],P3); atomicAdd(&Lbuf[3*DIM+d],L3);
  atomicAdd(&Pbuf[4*DIM+d],P4); atomicAdd(&Lbuf[4*DIM+d],L4);
  atomicAdd(&Pbuf[5*DIM+d],P5); atomicAdd(&Lbuf[5*DIM+d],L5);
  atomicAdd(&Pbuf[6*DIM+d],P6); atomicAdd(&Lbuf[6*DIM+d],L6);
  atomicAdd(&Pbuf[7*DIM+d],P7); atomicAdd(&Lbuf[7*DIM+d],L7);
}

// Single block, 1024 threads (was 256): per-class D_c, n_c;
// S_same = sum_c sum_d P_c*L_c; S_all = sum_d (sum_c P)(sum_c L).
// Column pass uses float4 loads (thread owns 4 consecutive d).
// One __syncthreads total; combine in fp64.
__global__ __launch_bounds__(1024) void k3_final(
    const float* __restrict__ diag, const int* __restrict__ labels,
    const float* __restrict__ Pbuf, const float* __restrict__ Lbuf,
    float* __restrict__ out){
  const int t = threadIdx.x;
  const int wave = t>>6, lane = t&63;

  __shared__ double sD[16][8];
  __shared__ int    sN[16][8];
  __shared__ double sS[16], sA[16];

  // ---- per-class diag sums and counts (2048 rows / 1024 threads = 2 iters) ----
  double Dl[8]; int Nl[8];
  #pragma unroll
  for(int c=0;c<8;c++){ Dl[c]=0.0; Nl[c]=0; }
  for(int i=t;i<N_ROWS;i+=1024){
    int lab = labels[i];
    double dg = (double)diag[i];
    #pragma unroll
    for(int c=0;c<8;c++){
      if(lab==c){ Dl[c]+=dg; Nl[c]++; }
    }
  }
  #pragma unroll
  for(int c=0;c<8;c++){
    #pragma unroll
    for(int o=32;o>0;o>>=1){
      Dl[c] += __shfl_xor(Dl[c],o,64);
      Nl[c] += __shfl_xor(Nl[c],o,64);
    }
  }
  if(lane==0){
    #pragma unroll
    for(int c=0;c<8;c++){ sD[wave][c]=Dl[c]; sN[wave][c]=Nl[c]; }
  }

  // ---- column pass: thread owns d in [4t, 4t+3], float4 loads ----
  double acc_same=0.0, acc_all=0.0;
  {
    const int base = t*4;
    double ps0=0,ps1=0,ps2=0,ps3=0, ls0=0,ls1=0,ls2=0,ls3=0;
    #pragma unroll
    for(int c=0;c<8;c++){
      float4 p4 = *(const float4*)&Pbuf[c*DIM + base];
      float4 l4 = *(const float4*)&Lbuf[c*DIM + base];
      acc_same += (double)p4.x*(double)l4.x + (double)p4.y*(double)l4.y
                + (double)p4.z*(double)l4.z + (double)p4.w*(double)l4.w;
      ps0 += p4.x; ps1 += p4.y; ps2 += p4.z; ps3 += p4.w;
      ls0 += l4.x; ls1 += l4.y; ls2 += l4.z; ls3 += l4.w;
    }
    acc_all = ps0*ls0 + ps1*ls1 + ps2*ls2 + ps3*ls3;
  }
  #pragma unroll
  for(int o=32;o>0;o>>=1){
    acc_same += __shfl_xor(acc_same,o,64);
    acc_all  += __shfl_xor(acc_all,o,64);
  }
  if(lane==0){ sS[wave]=acc_same; sA[wave]=acc_all; }
  __syncthreads();

  if(t==0){
    double D[8]; int Ncnt[8];
    #pragma unroll
    for(int c=0;c<8;c++){
      double d0=0.0; int n0=0;
      #pragma unroll
      for(int w=0;w<16;w++){ d0 += sD[w][c]; n0 += sN[w][c]; }
      D[c]=d0; Ncnt[c]=n0;
    }
    double S_same=0.0, S_all=0.0;
    #pragma unroll
    for(int w=0;w<16;w++){ S_same += sS[w]; S_all += sA[w]; }
    double same_num=0.0, diff_num=0.0;
    #pragma unroll
    for(int c=0;c<8;c++){
      same_num += (double)Ncnt[c]*D[c];
      diff_num += (double)(N_ROWS - Ncnt[c])*D[c];
    }
    same_num -= S_same;            // = same_sum * 2d
    diff_num -= (S_all - S_same);  // = diff_sum * 2d
    out[0] = (float)(same_num/diff_num);
  }
}

extern "C" void kernel_launch(void* const* d_in, const int* in_sizes, int n_in,
                              void* d_out, int out_size, void* d_ws, size_t ws_size,
                              hipStream_t stream){
  const float* feat   = (const float*)d_in[0];
  const int*   labels = (const int*)d_in[1];
  float* out = (float*)d_out;
  float* ws  = (float*)d_ws;
  float* lse  = ws;                    // 2048
  float* diag = ws + N_ROWS;           // 2048
  float* Pbuf = ws + 2*N_ROWS;         // 8*4096  (16 KiB offset -> float4 aligned)
  float* Lbuf = Pbuf + NCLS*DIM;       // 8*4096  (contiguous after Pbuf)

  k1_rowstats<<<N_ROWS, 256, 0, stream>>>(feat, lse, diag, Pbuf);
  k2_accum<<<dim3(DIM/256, N_ROWS/32), 256, 0, stream>>>(feat, lse, labels, Pbuf, Lbuf);
  k3_final<<<1, 1024, 0, stream>>>(diag, labels, Pbuf, Lbuf, out);
}

// Round 2
// 117.926 us; speedup vs baseline: 1.1228x; 1.0513x over previous
//
#include <hip/hip_runtime.h>
#include <cmath>

#define N_ROWS 2048
#define DIM 4096
#define ROW_STRIDE 8192   // features[:,0,:] -> row i at offset i*2*4096
#define NCLS 8

__device__ __forceinline__ float wred_sum(float v){
  #pragma unroll
  for(int o=32;o>0;o>>=1) v += __shfl_xor(v,o,64);
  return v;
}
__device__ __forceinline__ float wred_max(float v){
  #pragma unroll
  for(int o=32;o>0;o>>=1) v = fmaxf(v,__shfl_xor(v,o,64));
  return v;
}

// One block per row: compute lse[row] and diag[row] = sum p*logp in a single
// fused pass: S = sum e^{x-m}, T1 = sum (x-m)e^{x-m};
//   lse  = m + log S
//   diag = T1/S - log S
// Blocks 0..63 also zero the 65536-float P/L accumulator region.
__global__ __launch_bounds__(256) void k1_rowstats(
    const float* __restrict__ feat, float* __restrict__ lse,
    float* __restrict__ diag, float* __restrict__ zero_region){
  const int t = threadIdx.x;
  const int row = blockIdx.x;
  const int wave = t>>6, lane = t&63;
  if(row < 64){
    float4* z = (float4*)zero_region;
    z[row*256 + t] = make_float4(0.f,0.f,0.f,0.f);
  }
  const float4* x4 = (const float4*)(feat + (size_t)row * ROW_STRIDE);
  float4 v[4];
  #pragma unroll
  for(int k=0;k<4;k++) v[k] = x4[t + k*256];

  __shared__ float red[8];   // [0..3]=per-wave S (or max), [4..7]=per-wave T1
  // ---- max ----
  float m = -INFINITY;
  #pragma unroll
  for(int k=0;k<4;k++)
    m = fmaxf(m, fmaxf(fmaxf(v[k].x,v[k].y), fmaxf(v[k].z,v[k].w)));
  m = wred_max(m);
  if(lane==0) red[wave] = m;
  __syncthreads();
  m = fmaxf(fmaxf(red[0],red[1]), fmaxf(red[2],red[3]));
  __syncthreads();
  // ---- fused S and T1 ----
  float s = 0.f, t1 = 0.f;
  #pragma unroll
  for(int k=0;k<4;k++){
    float a=v[k].x-m, b=v[k].y-m, c=v[k].z-m, d2=v[k].w-m;
    float ea=__expf(a), eb=__expf(b), ec=__expf(c), ed=__expf(d2);
    s  += ea + eb + ec + ed;
    t1 += a*ea + b*eb + c*ec + d2*ed;
  }
  s  = wred_sum(s);
  t1 = wred_sum(t1);
  if(lane==0){ red[wave] = s; red[4+wave] = t1; }
  __syncthreads();
  if(t==0){
    float S  = red[0]+red[1]+red[2]+red[3];
    float T1 = red[4]+red[5]+red[6]+red[7];
    float lg = __logf(S);
    lse[row]  = m + lg;
    diag[row] = T1/S - lg;
  }
}

// grid (DIM/256, 32): thread owns column d, iterates a 64-row chunk in
// 4 batches of 16: phase A loads 16 x-values branch-free (16 loads in
// flight -> 32 KB/CU at 2 blocks/CU, saturating HBM), phase B does
// exp + per-class register accumulation. 16 global atomics per thread
// (2.1M total, 32 contenders/address).
__global__ __launch_bounds__(256,2) void k2_accum(
    const float* __restrict__ feat, const float* __restrict__ lse,
    const int* __restrict__ labels,
    float* __restrict__ Pbuf, float* __restrict__ Lbuf){
  const int d = blockIdx.x * 256 + threadIdx.x;
  const int r0 = blockIdx.y * 64;
  float P0=0,P1=0,P2=0,P3=0,P4=0,P5=0,P6=0,P7=0;
  float L0=0,L1=0,L2=0,L3=0,L4=0,L5=0,L6=0,L7=0;
  const float* col = feat + (size_t)r0 * ROW_STRIDE + d;
  for(int ib=0; ib<4; ib++){
    float xs[16];
    #pragma unroll
    for(int j=0;j<16;j++)
      xs[j] = col[(size_t)(ib*16+j) * ROW_STRIDE];
    #pragma unroll
    for(int j=0;j<16;j++){
      const int r = r0 + ib*16 + j;
      float v = xs[j] - lse[r];
      float e = __expf(v);
      int lab = __builtin_amdgcn_readfirstlane(labels[r]); // wave-uniform -> scalar branch
      switch(lab){
        case 0: P0+=e; L0+=v; break;
        case 1: P1+=e; L1+=v; break;
        case 2: P2+=e; L2+=v; break;
        case 3: P3+=e; L3+=v; break;
        case 4: P4+=e; L4+=v; break;
        case 5: P5+=e; L5+=v; break;
        case 6: P6+=e; L6+=v; break;
        default: P7+=e; L7+=v; break;
      }
    }
  }
  atomicAdd(&Pbuf[0*DIM+d],P0); atomicAdd(&Lbuf[0*DIM+d],L0);
  atomicAdd(&Pbuf[1*DIM+d],P1); atomicAdd(&Lbuf[1*DIM+d],L1);
  atomicAdd(&Pbuf[2*DIM+d],P2); atomicAdd(&Lbuf[2*DIM+d],L2);
  atomicAdd(&Pbuf[3*DIM+d],P3); atomicAdd(&Lbuf[3*DIM+d],L3);
  atomicAdd(&Pbuf[4*DIM+d],P4); atomicAdd(&Lbuf[4*DIM+d],L4);
  atomicAdd(&Pbuf[5*DIM+d],P5); atomicAdd(&Lbuf[5*DIM+d],L5);
  atomicAdd(&Pbuf[6*DIM+d],P6); atomicAdd(&Lbuf[6*DIM+d],L6);
  atomicAdd(&Pbuf[7*DIM+d],P7); atomicAdd(&Lbuf[7*DIM+d],L7);
}

// Single block, 1024 threads: per-class D_c, n_c;
// S_same = sum_c sum_d P_c*L_c; S_all = sum_d (sum_c P)(sum_c L).
// Column pass uses float4 loads (thread owns 4 consecutive d).
// One __syncthreads total; combine in fp64.
__global__ __launch_bounds__(1024) void k3_final(
    const float* __restrict__ diag, const int* __restrict__ labels,
    const float* __restrict__ Pbuf, const float* __restrict__ Lbuf,
    float* __restrict__ out){
  const int t = threadIdx.x;
  const int wave = t>>6, lane = t&63;

  __shared__ double sD[16][8];
  __shared__ int    sN[16][8];
  __shared__ double sS[16], sA[16];

  // ---- per-class diag sums and counts (2048 rows / 1024 threads = 2 iters) ----
  double Dl[8]; int Nl[8];
  #pragma unroll
  for(int c=0;c<8;c++){ Dl[c]=0.0; Nl[c]=0; }
  for(int i=t;i<N_ROWS;i+=1024){
    int lab = labels[i];
    double dg = (double)diag[i];
    #pragma unroll
    for(int c=0;c<8;c++){
      if(lab==c){ Dl[c]+=dg; Nl[c]++; }
    }
  }
  #pragma unroll
  for(int c=0;c<8;c++){
    #pragma unroll
    for(int o=32;o>0;o>>=1){
      Dl[c] += __shfl_xor(Dl[c],o,64);
      Nl[c] += __shfl_xor(Nl[c],o,64);
    }
  }
  if(lane==0){
    #pragma unroll
    for(int c=0;c<8;c++){ sD[wave][c]=Dl[c]; sN[wave][c]=Nl[c]; }
  }

  // ---- column pass: thread owns d in [4t, 4t+3], float4 loads ----
  double acc_same=0.0, acc_all=0.0;
  {
    const int base = t*4;
    double ps0=0,ps1=0,ps2=0,ps3=0, ls0=0,ls1=0,ls2=0,ls3=0;
    #pragma unroll
    for(int c=0;c<8;c++){
      float4 p4 = *(const float4*)&Pbuf[c*DIM + base];
      float4 l4 = *(const float4*)&Lbuf[c*DIM + base];
      acc_same += (double)p4.x*(double)l4.x + (double)p4.y*(double)l4.y
                + (double)p4.z*(double)l4.z + (double)p4.w*(double)l4.w;
      ps0 += p4.x; ps1 += p4.y; ps2 += p4.z; ps3 += p4.w;
      ls0 += l4.x; ls1 += l4.y; ls2 += l4.z; ls3 += l4.w;
    }
    acc_all = ps0*ls0 + ps1*ls1 + ps2*ls2 + ps3*ls3;
  }
  #pragma unroll
  for(int o=32;o>0;o>>=1){
    acc_same += __shfl_xor(acc_same,o,64);
    acc_all  += __shfl_xor(acc_all,o,64);
  }
  if(lane==0){ sS[wave]=acc_same; sA[wave]=acc_all; }
  __syncthreads();

  if(t==0){
    double D[8]; int Ncnt[8];
    #pragma unroll
    for(int c=0;c<8;c++){
      double d0=0.0; int n0=0;
      #pragma unroll
      for(int w=0;w<16;w++){ d0 += sD[w][c]; n0 += sN[w][c]; }
      D[c]=d0; Ncnt[c]=n0;
    }
    double S_same=0.0, S_all=0.0;
    #pragma unroll
    for(int w=0;w<16;w++){ S_same += sS[w]; S_all += sA[w]; }
    double same_num=0.0, diff_num=0.0;
    #pragma unroll
    for(int c=0;c<8;c++){
      same_num += (double)Ncnt[c]*D[c];
      diff_num += (double)(N_ROWS - Ncnt[c])*D[c];
    }
    same_num -= S_same;            // = same_sum * 2d
    diff_num -= (S_all - S_same);  // = diff_sum * 2d
    out[0] = (float)(same_num/diff_num);
  }
}

extern "C" void kernel_launch(void* const* d_in, const int* in_sizes, int n_in,
                              void* d_out, int out_size, void* d_ws, size_t ws_size,
                              hipStream_t stream){
  const float* feat   = (const float*)d_in[0];
  const int*   labels = (const int*)d_in[1];
  float* out = (float*)d_out;
  float* ws  = (float*)d_ws;
  float* lse  = ws;                    // 2048
  float* diag = ws + N_ROWS;           // 2048
  float* Pbuf = ws + 2*N_ROWS;         // 8*4096  (16 KiB offset -> float4 aligned)
  float* Lbuf = Pbuf + NCLS*DIM;       // 8*4096  (contiguous after Pbuf)

  k1_rowstats<<<N_ROWS, 256, 0, stream>>>(feat, lse, diag, Pbuf);
  k2_accum<<<dim3(DIM/256, N_ROWS/64), 256, 0, stream>>>(feat, lse, labels, Pbuf, Lbuf);
  k3_final<<<1, 1024, 0, stream>>>(diag, labels, Pbuf, Lbuf, out);
}